// Round 6
// baseline (524.708 us; speedup 1.0000x reference)
//
#include <hip/hip_runtime.h>
#include <math.h>

typedef _Float16 f16;
typedef _Float16 half4 __attribute__((ext_vector_type(4)));
typedef _Float16 half8 __attribute__((ext_vector_type(8)));
typedef float f32x4 __attribute__((ext_vector_type(4)));

#define NK 256
#define LW 249
#define WHS 256          // Wh row stride (f16, zero-padded)
#define TLEN 2000
#define PAD 124
#define NCOPY 8
#define CPL 2328         // elems/copy; dword stride 1164 == 12 mod 32 -> conflict-free b128
#define CPWRITE 2304
#define THREADS 1024

// ws layout (bytes)
#define WS_BIASP (NK * WHS * 2)        // after Wh
#define WS_PERM  (WS_BIASP + NK * 4)
#define WS_TM    (WS_PERM + NK * 4)

// ---- prep: tap-extent scan, M-bucket counting sort, permuted f16 W ----
// Within-bucket order comes from LDS atomics (non-deterministic order), but the
// OUTPUT is bitwise identical for any order: skipped k-blocks have all-zero A
// rows and contribute exact +0.0f to the f32 accumulator; cnt/max are order-free.
__global__ __launch_bounds__(256) void prep(const float* __restrict__ W,
                                            const float* __restrict__ bias,
                                            f16* __restrict__ Wh,
                                            float* __restrict__ biasP,
                                            int* __restrict__ perm,
                                            int* __restrict__ tileM) {
  __shared__ int s_m[NK];
  __shared__ int s_perm[NK];
  __shared__ int s_cnt[8], s_cur[8];
  const int k = threadIdx.x;

  int first = -1, last = -1;
  for (int l = 0; l < LW; ++l) {
    const float w = W[k * LW + l];
    if (w != 0.0f) { if (first < 0) first = l; last = l; }
  }
  if (first < 0) { first = 124; last = 124; }
  const int lo = first >> 5, hi = (last >> 5) + 1;
  int M = max(4 - lo, hi - 4);
  M = min(max(M, 1), 4);          // taps are centered -> window [4-M, 4+M)
  s_m[k] = M;
  if (k < 8) s_cnt[k] = 0;
  __syncthreads();
  atomicAdd(&s_cnt[M], 1);
  __syncthreads();
  if (k == 0) {
    int run = 0;
    for (int b = 0; b < 8; ++b) { s_cur[b] = run; run += s_cnt[b]; }
  }
  __syncthreads();
  const int pos = atomicAdd(&s_cur[M], 1);
  s_perm[pos] = k;                 // sorted ascending by M
  __syncthreads();

  perm[k]  = s_perm[k];
  biasP[k] = bias[s_perm[k]];
  if (k < 16) {
    int mM = 1;
    for (int j = 0; j < 16; ++j) mM = max(mM, s_m[s_perm[k * 16 + j]]);
    tileM[k] = mM;
  }
  // permuted f16 weights, row-cooperative (coalesced)
  for (int r = 0; r < NK; ++r) {
    const int src = s_perm[r];
    const float v = (k < LW) ? W[src * LW + k] : 0.0f;
    Wh[r * WHS + k] = (f16)v;
  }
}

// ---- per-wave templated main loop: kb window [4-M, 4+M), ring of 8 ----
template <int M>
__device__ __forceinline__ void run_tile(const f16* xc, const f16* __restrict__ Wh,
                                         const float* __restrict__ biasP,
                                         const int* __restrict__ perm,
                                         float* __restrict__ out,
                                         int bc, int tile, int l15, int lq, int cpyPart) {
  constexpr int KLO = 4 - M;
  half8 af[2 * M];
#pragma unroll
  for (int a = 0; a < 2 * M; ++a)
    af[a] = *(const half8*)&Wh[(tile * 16 + l15) * WHS + (KLO + a) * 32 + 8 * lq];

  float thr[4];
#pragma unroll
  for (int r = 0; r < 4; ++r) thr[r] = -biasP[tile * 16 + lq * 4 + r];

  int cnt[4]; float mx[4];
#pragma unroll
  for (int r = 0; r < 4; ++r) { cnt[r] = 0; mx[r] = -INFINITY; }

  for (int p = 0; p < 2; ++p) {     // nt parity, sequential
    const int b0 = cpyPart + p * 16;
    half8 R[8];
#pragma unroll
    for (int kb = 0; kb < 8; ++kb) R[kb] = *(const half8*)&xc[b0 + kb * 32];

    for (int it = 0; it < 8; ++it) {
#pragma unroll
      for (int ui = 0; ui < 8; ++ui) {
        const int u  = it * 8 + ui;
        const int nt = p + 2 * u;
        f32x4 acc = (f32x4){0.0f, 0.0f, 0.0f, 0.0f};
#pragma unroll
        for (int a = 0; a < 2 * M; ++a) {
          const int kb = KLO + a;
          acc = __builtin_amdgcn_mfma_f32_16x16x32_f16(af[a], R[(ui + kb) & 7], acc, 0, 0, 0);
        }
        R[ui] = *(const half8*)&xc[b0 + 32 * u + 256];   // slide (dead at u=63, in-bounds)
        if (nt <= 124) {
#pragma unroll
          for (int r = 0; r < 4; ++r) {
            const float v = acc[r];
            cnt[r] += (v > thr[r]) ? 1 : 0;
            mx[r]   = fmaxf(mx[r], v);
          }
        }
      }
    }
  }

  // reduce over the 16 lanes sharing each k, then write via perm
#pragma unroll
  for (int r = 0; r < 4; ++r) {
    float c0 = (float)cnt[r], m0 = mx[r];
#pragma unroll
    for (int s = 1; s < 16; s <<= 1) {
      c0 += __shfl_xor(c0, s, 16);
      m0  = fmaxf(m0, __shfl_xor(m0, s, 16));
    }
    if (l15 == 0) {
      const int ko = perm[tile * 16 + lq * 4 + r];
      float2 res;
      res.x = c0 * (1.0f / (float)TLEN);
      res.y = m0 - thr[r];          // + bias
      *(float2*)&out[bc * (2 * NK) + 2 * ko] = res;
    }
  }
}

__global__ __launch_bounds__(THREADS, 4) void rocket_mfma(
    const float* __restrict__ x, const f16* __restrict__ Wh,
    const float* __restrict__ biasP, const int* __restrict__ perm,
    const int* __restrict__ tileM, float* __restrict__ out) {
  __shared__ f16 xc[NCOPY * CPL];

  const int bc   = blockIdx.x;
  const int tid  = threadIdx.x;
  const int wid  = tid >> 6;
  const int lane = tid & 63;
  const int l15  = lane & 15;
  const int lq   = lane >> 4;

  // stage 8 shifted f16 copies of the padded row
  const float* xrow = x + bc * TLEN;
  for (int q = tid * 4; q < NCOPY * CPWRITE; q += THREADS * 4) {
    const int cpy = q / CPWRITE;
    const int i   = q - cpy * CPWRITE;
    half4 v;
#pragma unroll
    for (int r = 0; r < 4; ++r) {
      const int j = i + r + cpy - PAD;
      v[r] = (j >= 0 && j < TLEN) ? (f16)xrow[j] : (f16)0.0f;
    }
    *(half4*)&xc[cpy * CPL + i] = v;
  }
  __syncthreads();

  // snake tile assignment: SIMD s (= wid&3) gets tiles {15-s, 8+s, 7-s, s}
  const int jj = wid >> 2, ss = wid & 3;
  const int tile = (jj == 0) ? (15 - ss) : (jj == 1) ? (8 + ss)
                 : (jj == 2) ? (7 - ss)  : ss;
  const int M = __builtin_amdgcn_readfirstlane(tileM[tile]);

  const int lane_e   = 8 * lq + l15;
  const int cpy      = l15 & 7;
  const int cpyPart  = cpy * CPL + (lane_e - cpy);

  switch (M) {
    case 1:  run_tile<1>(xc, Wh, biasP, perm, out, bc, tile, l15, lq, cpyPart); break;
    case 2:  run_tile<2>(xc, Wh, biasP, perm, out, bc, tile, l15, lq, cpyPart); break;
    case 3:  run_tile<3>(xc, Wh, biasP, perm, out, bc, tile, l15, lq, cpyPart); break;
    default: run_tile<4>(xc, Wh, biasP, perm, out, bc, tile, l15, lq, cpyPart); break;
  }
}

extern "C" void kernel_launch(void* const* d_in, const int* in_sizes, int n_in,
                              void* d_out, int out_size, void* d_ws, size_t ws_size,
                              hipStream_t stream) {
  const float* x    = (const float*)d_in[0];   // (8,32,2000)
  const float* W    = (const float*)d_in[1];   // (256,249)
  const float* bias = (const float*)d_in[2];   // (256,)
  float* out = (float*)d_out;                  // (8,32,512)

  f16*   Wh    = (f16*)d_ws;
  float* biasP = (float*)((char*)d_ws + WS_BIASP);
  int*   perm  = (int*)((char*)d_ws + WS_PERM);
  int*   tileM = (int*)((char*)d_ws + WS_TM);

  prep<<<1, 256, 0, stream>>>(W, bias, Wh, biasP, perm, tileM);
  rocket_mfma<<<256, THREADS, 0, stream>>>(x, Wh, biasP, perm, tileM, out);
}